// Round 1
// baseline (10057.105 us; speedup 1.0000x reference)
//
#include <hip/hip_runtime.h>
#include <math.h>

#define N_NODES 11616
#define NHID    512
#define EDGES   371712
#define S0 4278
#define S1 2081
#define S2 5257
#define F0 3066
#define F1 2081
#define F2 5257

// ---------------- init: zero accumulators / degree / cursor ----------------
__global__ void k_init(double* __restrict__ accum, int* __restrict__ indeg,
                       int* __restrict__ cursor)
{
    int i = blockIdx.x * blockDim.x + threadIdx.x;
    if (i < 2) accum[i] = 0.0;
    if (i < N_NODES) { indeg[i] = 0; cursor[i] = 0; }
}

// ---------------- CSR build ----------------
__global__ void k_count(const int* __restrict__ dst, int* __restrict__ indeg)
{
    int e = blockIdx.x * blockDim.x + threadIdx.x;
    if (e < EDGES) atomicAdd(&indeg[dst[e]], 1);
}

__global__ void k_scan(const int* __restrict__ indeg, int* __restrict__ rowptr)
{
    __shared__ int part[256];
    const int t = threadIdx.x;
    const int chunk = (N_NODES + 255) / 256;   // 46
    const int base = t * chunk;
    int s = 0;
    for (int i = 0; i < chunk; ++i) {
        int idx = base + i;
        if (idx < N_NODES) s += indeg[idx];
    }
    part[t] = s;
    __syncthreads();
    if (t == 0) {
        for (int i = 1; i < 256; ++i) part[i] += part[i - 1];
    }
    __syncthreads();
    int run = (t == 0) ? 0 : part[t - 1];
    for (int i = 0; i < chunk; ++i) {
        int idx = base + i;
        if (idx < N_NODES) { rowptr[idx] = run; run += indeg[idx]; }
    }
    if (t == 0) rowptr[N_NODES] = part[255];
}

__global__ void k_fill(const int* __restrict__ src, const int* __restrict__ dst,
                       const float* __restrict__ ew, const int* __restrict__ rowptr,
                       int* __restrict__ cursor, int* __restrict__ csrc,
                       float* __restrict__ cw)
{
    int e = blockIdx.x * blockDim.x + threadIdx.x;
    if (e >= EDGES) return;
    int d = dst[e];
    int pos = rowptr[d] + atomicAdd(&cursor[d], 1);
    csrc[pos] = src[e];
    cw[pos]   = ew[e];
}

// ---------------- generic fp32 tiled GEMM: C = A(MxK) @ B(KxNN) + bias ----------------
// 64x64 tile, BK=16, 256 threads, 4x4 microtile per thread.
__global__ void k_gemm(const float* __restrict__ A, const float* __restrict__ B,
                       const float* __restrict__ bias, float* __restrict__ C,
                       int M, int K, int NN)
{
    __shared__ float As[16][65];
    __shared__ float Bs[16][65];
    const int t  = threadIdx.x;
    const int tx = t & 15, ty = t >> 4;
    const int rowBase = blockIdx.y * 64;
    const int colBase = blockIdx.x * 64;
    const int aRow = t >> 2;          // 0..63
    const int aCol = (t & 3) << 2;    // 0,4,8,12
    const int bRow = t >> 4;          // 0..15
    const int bCol = (t & 15) << 2;   // 0..60
    float acc[4][4] = {};
    for (int k0 = 0; k0 < K; k0 += 16) {
        const int ar = rowBase + aRow;
        #pragma unroll
        for (int j = 0; j < 4; ++j) {
            int ak = k0 + aCol + j;
            As[aCol + j][aRow] = (ar < M && ak < K) ? A[(long)ar * K + ak] : 0.f;
        }
        const int bk = k0 + bRow;
        #pragma unroll
        for (int j = 0; j < 4; ++j) {
            int bc = colBase + bCol + j;
            Bs[bRow][bCol + j] = (bk < K && bc < NN) ? B[(long)bk * NN + bc] : 0.f;
        }
        __syncthreads();
        #pragma unroll
        for (int k = 0; k < 16; ++k) {
            float a[4], b[4];
            #pragma unroll
            for (int i = 0; i < 4; ++i) a[i] = As[k][ty * 4 + i];
            #pragma unroll
            for (int j = 0; j < 4; ++j) b[j] = Bs[k][tx * 4 + j];
            #pragma unroll
            for (int i = 0; i < 4; ++i)
                #pragma unroll
                for (int j = 0; j < 4; ++j)
                    acc[i][j] = fmaf(a[i], b[j], acc[i][j]);
        }
        __syncthreads();
    }
    #pragma unroll
    for (int i = 0; i < 4; ++i) {
        int r = rowBase + ty * 4 + i;
        if (r >= M) continue;
        #pragma unroll
        for (int j = 0; j < 4; ++j) {
            int c = colBase + tx * 4 + j;
            if (c < NN) C[(long)r * NN + c] = acc[i][j] + (bias ? bias[c] : 0.f);
        }
    }
}

// ---------------- SpMM gather + bias + residual/relu ----------------
// one block (128 threads) per dst node; each thread owns 4 channels (float4)
__global__ void k_spmm(const float* __restrict__ y, const float* __restrict__ xold,
                       const int* __restrict__ rowptr, const int* __restrict__ csrc,
                       const float* __restrict__ cw, const float* __restrict__ bias,
                       int do_relu, float* __restrict__ xnew)
{
    const int n  = blockIdx.x;
    const int c0 = threadIdx.x << 2;
    float4 s = make_float4(0.f, 0.f, 0.f, 0.f);
    const int beg = rowptr[n], end = rowptr[n + 1];
    for (int e = beg; e < end; ++e) {
        const int   sn = csrc[e];
        const float w  = cw[e];
        const float4 yv = *reinterpret_cast<const float4*>(y + (long)sn * NHID + c0);
        s.x = fmaf(w, yv.x, s.x);
        s.y = fmaf(w, yv.y, s.y);
        s.z = fmaf(w, yv.z, s.z);
        s.w = fmaf(w, yv.w, s.w);
    }
    const float4 bv = *reinterpret_cast<const float4*>(bias + c0);
    float4 o;
    if (do_relu) {
        o.x = fmaxf(s.x + bv.x, 0.f);
        o.y = fmaxf(s.y + bv.y, 0.f);
        o.z = fmaxf(s.z + bv.z, 0.f);
        o.w = fmaxf(s.w + bv.w, 0.f);
    } else {
        const float4 xv = *reinterpret_cast<const float4*>(xold + (long)n * NHID + c0);
        o.x = xv.x + s.x + bv.x;
        o.y = xv.y + s.y + bv.y;
        o.z = xv.z + s.z + bv.z;
        o.w = xv.w + s.w + bv.w;
    }
    *reinterpret_cast<float4*>(xnew + (long)n * NHID + c0) = o;
}

// ---------------- z = x @ x^T fused emb-loss ----------------
// emb contribution per element: softplus(z) - adj*z  (exact for adj in {0,1})
__global__ void k_zloss(const float* __restrict__ x, const float* __restrict__ adj,
                        double* __restrict__ accum)
{
    __shared__ float As[16][65];
    __shared__ float Bs[16][65];
    __shared__ float red[256];
    const int t  = threadIdx.x;
    const int tx = t & 15, ty = t >> 4;
    const int rowBase = blockIdx.y * 64;
    const int colBase = blockIdx.x * 64;
    const int lr = t >> 2;
    const int lc = (t & 3) << 2;
    const int arow = rowBase + lr;
    const int brow = colBase + lr;
    float acc[4][4] = {};
    for (int k0 = 0; k0 < NHID; k0 += 16) {
        #pragma unroll
        for (int j = 0; j < 4; ++j) {
            int kk = k0 + lc + j;
            As[lc + j][lr] = (arow < N_NODES) ? x[(long)arow * NHID + kk] : 0.f;
            Bs[lc + j][lr] = (brow < N_NODES) ? x[(long)brow * NHID + kk] : 0.f;
        }
        __syncthreads();
        #pragma unroll
        for (int k = 0; k < 16; ++k) {
            float a[4], b[4];
            #pragma unroll
            for (int i = 0; i < 4; ++i) a[i] = As[k][ty * 4 + i];
            #pragma unroll
            for (int j = 0; j < 4; ++j) b[j] = Bs[k][tx * 4 + j];
            #pragma unroll
            for (int i = 0; i < 4; ++i)
                #pragma unroll
                for (int j = 0; j < 4; ++j)
                    acc[i][j] = fmaf(a[i], b[j], acc[i][j]);
        }
        __syncthreads();
    }
    float local = 0.f;
    #pragma unroll
    for (int i = 0; i < 4; ++i) {
        int r = rowBase + ty * 4 + i;
        #pragma unroll
        for (int j = 0; j < 4; ++j) {
            int c = colBase + tx * 4 + j;
            if (r < N_NODES && c < N_NODES) {
                float z  = acc[i][j];
                float sp = fmaxf(z, 0.f) + log1pf(expf(-fabsf(z)));
                local += sp - adj[(long)r * N_NODES + c] * z;
            }
        }
    }
    red[t] = local;
    __syncthreads();
    for (int sft = 128; sft > 0; sft >>= 1) {
        if (t < sft) red[t] += red[t + sft];
        __syncthreads();
    }
    if (t == 0) atomicAdd(accum, (double)red[0]);
}

// ---------------- recon loss ----------------
__global__ void k_recon(const float* __restrict__ r0, const float* __restrict__ X0,
                        double* __restrict__ accum)
{
    const int row = blockIdx.x;
    const int t = threadIdx.x;   // 256
    float dot = 0.f, nr = 0.f, nf = 0.f;
    for (int c = t; c < F0; c += 256) {
        float a = r0[(long)row * F0 + c];
        float b = X0[(long)row * F0 + c];
        dot = fmaf(a, b, dot);
        nr  = fmaf(a, a, nr);
        nf  = fmaf(b, b, nf);
    }
    #pragma unroll
    for (int o = 32; o > 0; o >>= 1) {
        dot += __shfl_down(dot, o);
        nr  += __shfl_down(nr, o);
        nf  += __shfl_down(nf, o);
    }
    __shared__ float sd[3][4];
    const int lane = t & 63, wid = t >> 6;
    if (lane == 0) { sd[0][wid] = dot; sd[1][wid] = nr; sd[2][wid] = nf; }
    __syncthreads();
    if (t == 0) {
        float d = sd[0][0] + sd[0][1] + sd[0][2] + sd[0][3];
        float a = sd[1][0] + sd[1][1] + sd[1][2] + sd[1][3];
        float b = sd[2][0] + sd[2][1] + sd[2][2] + sd[2][3];
        float cosv = d / (fmaxf(sqrtf(a), 1e-12f) * fmaxf(sqrtf(b), 1e-12f));
        float v = 1.f - cosv;
        atomicAdd(accum + 1, (double)(v * v * v));
    }
}

__global__ void k_final(const double* __restrict__ accum, float* __restrict__ out)
{
    if (threadIdx.x == 0) {
        out[45082958] = (float)(accum[0] / ((double)N_NODES * (double)N_NODES));
        out[45082959] = (float)(accum[1] / (double)S0);
    }
}

extern "C" void kernel_launch(void* const* d_in, const int* in_sizes, int n_in,
                              void* d_out, int out_size, void* d_ws, size_t ws_size,
                              hipStream_t stream)
{
    const float* X0  = (const float*)d_in[0];
    const float* X1  = (const float*)d_in[1];
    const float* X2  = (const float*)d_in[2];
    const int*   src = (const int*)d_in[3];
    const int*   dst = (const int*)d_in[4];
    const float* ew  = (const float*)d_in[5];
    const float* adj = (const float*)d_in[6];
    const float* fcW[3]  = {(const float*)d_in[7],  (const float*)d_in[9],  (const float*)d_in[11]};
    const float* fcB[3]  = {(const float*)d_in[8],  (const float*)d_in[10], (const float*)d_in[12]};
    const float* encW = (const float*)d_in[13];
    const float* encB = (const float*)d_in[14];
    const float* decW = (const float*)d_in[15];
    const float* decB = (const float*)d_in[16];
    const float* outW[3] = {(const float*)d_in[17], (const float*)d_in[19], (const float*)d_in[21]};
    const float* outB[3] = {(const float*)d_in[18], (const float*)d_in[20], (const float*)d_in[22]};
    float* out = (float*)d_out;

    char* ws = (char*)d_ws;
    size_t off = 0;
    double* accum = (double*)(ws); off += 16;
    const size_t XB = (size_t)N_NODES * NHID * sizeof(float);
    float* xbuf = (float*)(ws + off); off += XB;
    float* ybuf = (float*)(ws + off); off += XB;
    float* xalt = (float*)(ws + off); off += XB;
    int* indeg  = (int*)(ws + off);   off += ((size_t)N_NODES * 4 + 15) & ~(size_t)15;
    int* rowptr = (int*)(ws + off);   off += ((size_t)(N_NODES + 1) * 4 + 15) & ~(size_t)15;
    int* cursor = (int*)(ws + off);   off += ((size_t)N_NODES * 4 + 15) & ~(size_t)15;
    int* csrc   = (int*)(ws + off);   off += (size_t)EDGES * 4;
    float* cw   = (float*)(ws + off); off += (size_t)EDGES * 4;

    // ---- CSR build ----
    k_init<<<dim3((N_NODES + 255) / 256), dim3(256), 0, stream>>>(accum, indeg, cursor);
    k_count<<<dim3((EDGES + 255) / 256), dim3(256), 0, stream>>>(dst, indeg);
    k_scan<<<dim3(1), dim3(256), 0, stream>>>(indeg, rowptr);
    k_fill<<<dim3((EDGES + 255) / 256), dim3(256), 0, stream>>>(src, dst, ew, rowptr, cursor, csrc, cw);

    // ---- input FCs -> xbuf (concatenated) ----
    auto grid = [](int m, int nn) { return dim3((unsigned)((nn + 63) / 64), (unsigned)((m + 63) / 64)); };
    k_gemm<<<grid(S0, NHID), dim3(256), 0, stream>>>(X0, fcW[0], fcB[0], xbuf, S0, F0, NHID);
    k_gemm<<<grid(S1, NHID), dim3(256), 0, stream>>>(X1, fcW[1], fcB[1], xbuf + (size_t)S0 * NHID, S1, F1, NHID);
    k_gemm<<<grid(S2, NHID), dim3(256), 0, stream>>>(X2, fcW[2], fcB[2], xbuf + (size_t)(S0 + S1) * NHID, S2, F2, NHID);

    // ---- 8 GNN layers ----
    float* x  = xbuf;
    float* xn = xalt;
    for (int phase = 0; phase < 2; ++phase) {
        const float* W = phase ? decW : encW;
        const float* B = phase ? decB : encB;
        for (int i = 0; i < 4; ++i) {
            k_gemm<<<grid(N_NODES, NHID), dim3(256), 0, stream>>>(
                x, W + (size_t)i * NHID * NHID, nullptr, ybuf, N_NODES, NHID, NHID);
            k_spmm<<<dim3(N_NODES), dim3(128), 0, stream>>>(
                ybuf, x, rowptr, csrc, cw, B + (size_t)i * NHID, (i == 0) ? 1 : 0, xn);
            float* tmp = x; x = xn; xn = tmp;
        }
    }

    // ---- output projections ----
    k_gemm<<<grid(S0, F0), dim3(256), 0, stream>>>(x, outW[0], outB[0], out, S0, NHID, F0);
    k_gemm<<<grid(S1, F1), dim3(256), 0, stream>>>(x + (size_t)S0 * NHID, outW[1], outB[1],
                                                   out + (size_t)S0 * F0, S1, NHID, F1);
    k_gemm<<<grid(S2, F2), dim3(256), 0, stream>>>(x + (size_t)(S0 + S1) * NHID, outW[2], outB[2],
                                                   out + (size_t)S0 * F0 + (size_t)S1 * F1, S2, NHID, F2);

    // ---- losses ----
    k_zloss<<<dim3((N_NODES + 63) / 64, (N_NODES + 63) / 64), dim3(256), 0, stream>>>(x, adj, accum);
    k_recon<<<dim3(S0), dim3(256), 0, stream>>>(out, X0, accum);
    k_final<<<dim3(1), dim3(64), 0, stream>>>(accum, out);
}

// Round 2
// 5265.826 us; speedup vs baseline: 1.9099x; 1.9099x over previous
//
#include <hip/hip_runtime.h>
#include <math.h>

#define N_NODES 11616
#define NHID    512
#define EDGES   371712
#define S0 4278
#define S1 2081
#define S2 5257
#define F0 3066
#define F1 2081
#define F2 5257

typedef __attribute__((ext_vector_type(8))) short bf16x8;
typedef __attribute__((ext_vector_type(4))) float f32x4;

// ---------------- init ----------------
__global__ void k_init(double* __restrict__ accum, int* __restrict__ indeg,
                       int* __restrict__ cursor)
{
    int i = blockIdx.x * blockDim.x + threadIdx.x;
    if (i < 2) accum[i] = 0.0;
    if (i < N_NODES) { indeg[i] = 0; cursor[i] = 0; }
}

// ---------------- CSR build ----------------
__global__ void k_count(const int* __restrict__ dst, int* __restrict__ indeg)
{
    int e = blockIdx.x * blockDim.x + threadIdx.x;
    if (e < EDGES) atomicAdd(&indeg[dst[e]], 1);
}

__global__ void k_scan(const int* __restrict__ indeg, int* __restrict__ rowptr)
{
    __shared__ int part[256];
    const int t = threadIdx.x;
    const int chunk = (N_NODES + 255) / 256;
    const int base = t * chunk;
    int s = 0;
    for (int i = 0; i < chunk; ++i) {
        int idx = base + i;
        if (idx < N_NODES) s += indeg[idx];
    }
    part[t] = s;
    __syncthreads();
    if (t == 0) for (int i = 1; i < 256; ++i) part[i] += part[i - 1];
    __syncthreads();
    int run = (t == 0) ? 0 : part[t - 1];
    for (int i = 0; i < chunk; ++i) {
        int idx = base + i;
        if (idx < N_NODES) { rowptr[idx] = run; run += indeg[idx]; }
    }
    if (t == 0) rowptr[N_NODES] = part[255];
}

__global__ void k_fill(const int* __restrict__ src, const int* __restrict__ dst,
                       const float* __restrict__ ew, const int* __restrict__ rowptr,
                       int* __restrict__ cursor, int* __restrict__ csrc,
                       float* __restrict__ cw)
{
    int e = blockIdx.x * blockDim.x + threadIdx.x;
    if (e >= EDGES) return;
    int d = dst[e];
    int pos = rowptr[d] + atomicAdd(&cursor[d], 1);
    csrc[pos] = src[e];
    cw[pos]   = ew[e];
}

// ---------------- fp32 tiled transpose: out[C][R] = in[R][C]^T ----------------
__global__ void k_transpose(const float* __restrict__ in, float* __restrict__ out,
                            int R, int C)
{
    __shared__ float tile[32][33];
    const int cb = blockIdx.x * 32, rb = blockIdx.y * 32;
    const int tx = threadIdx.x, ty = threadIdx.y;   // 32 x 8
    #pragma unroll
    for (int i = ty; i < 32; i += 8) {
        int r = rb + i, c = cb + tx;
        tile[i][tx] = (r < R && c < C) ? in[(long)r * C + c] : 0.f;
    }
    __syncthreads();
    #pragma unroll
    for (int i = ty; i < 32; i += 8) {
        int r = cb + i, c = rb + tx;
        if (r < C && c < R) out[(long)r * R + c] = tile[tx][i];
    }
}

// ---------------- bf16 hi/lo split (RNE both halves) ----------------
__device__ __forceinline__ void split_bf16(float f, short& hi, short& lo)
{
    unsigned u  = __float_as_uint(f);
    unsigned hr = (u + 0x7FFFu + ((u >> 16) & 1u)) & 0xFFFF0000u;
    float    fh = __uint_as_float(hr);
    float    fl = f - fh;
    unsigned ul = __float_as_uint(fl);
    unsigned lr = ul + 0x7FFFu + ((ul >> 16) & 1u);
    hi = (short)(hr >> 16);
    lo = (short)(lr >> 16);
}

// stage one 128x32 fp32 panel (rows of P, contiguous k) into hi/lo bf16 LDS panels
// layout: Ph[g][row][j] holds P[rowBase+row][k0+g*8+j]
__device__ __forceinline__ void stage_panel(const float* __restrict__ P, int ld,
                                            int rows, int K, int rowBase, int k0,
                                            short (*Ph)[128][8], short (*Pl)[128][8],
                                            int t)
{
    #pragma unroll
    for (int it = 0; it < 2; ++it) {
        int p = t + it * 256;          // 0..511
        int m = p >> 2, g = p & 3;
        int row = rowBase + m;
        bf16x8 hv, lv;
        if (row < rows) {
            const float* rp = P + (long)row * ld + k0 + g * 8;
            #pragma unroll
            for (int j = 0; j < 8; ++j) {
                int k = k0 + g * 8 + j;
                float f = (k < K) ? rp[j] : 0.f;
                short h, l;
                split_bf16(f, h, l);
                hv[j] = h; lv[j] = l;
            }
        } else {
            #pragma unroll
            for (int j = 0; j < 8; ++j) { hv[j] = 0; lv[j] = 0; }
        }
        *(bf16x8*)(&Ph[g][m][0]) = hv;
        *(bf16x8*)(&Pl[g][m][0]) = lv;
    }
}

// ---------------- MFMA split GEMM: C = A(MxK) @ Bt(NNxK)^T + bias ----------------
__global__ __launch_bounds__(256, 2)
void k_gemm_bt(const float* __restrict__ A, const float* __restrict__ Bt,
               const float* __restrict__ bias, float* __restrict__ C,
               int M, int K, int NN)
{
    __shared__ short Ah[4][128][8], Al[4][128][8], Bh[4][128][8], Bl[4][128][8];
    const int t = threadIdx.x;
    const int rowBase = blockIdx.y * 128, colBase = blockIdx.x * 128;
    const int lane = t & 63, w = t >> 6;
    const int wm = (w >> 1) * 64, wn = (w & 1) * 64;
    const int g = lane >> 4, fr = lane & 15;

    f32x4 acc[4][4];
    #pragma unroll
    for (int i = 0; i < 4; ++i)
        #pragma unroll
        for (int j = 0; j < 4; ++j)
            acc[i][j] = (f32x4){0.f, 0.f, 0.f, 0.f};

    for (int k0 = 0; k0 < K; k0 += 32) {
        stage_panel(A,  K, M,  K, rowBase, k0, Ah, Al, t);
        stage_panel(Bt, K, NN, K, colBase, k0, Bh, Bl, t);
        __syncthreads();
        bf16x8 ah[4], al[4], bh[4], bl[4];
        #pragma unroll
        for (int f = 0; f < 4; ++f) {
            ah[f] = *(const bf16x8*)&Ah[g][wm + f * 16 + fr][0];
            al[f] = *(const bf16x8*)&Al[g][wm + f * 16 + fr][0];
            bh[f] = *(const bf16x8*)&Bh[g][wn + f * 16 + fr][0];
            bl[f] = *(const bf16x8*)&Bl[g][wn + f * 16 + fr][0];
        }
        #pragma unroll
        for (int i = 0; i < 4; ++i)
            #pragma unroll
            for (int j = 0; j < 4; ++j) {
                acc[i][j] = __builtin_amdgcn_mfma_f32_16x16x32_bf16(ah[i], bh[j], acc[i][j], 0, 0, 0);
                acc[i][j] = __builtin_amdgcn_mfma_f32_16x16x32_bf16(ah[i], bl[j], acc[i][j], 0, 0, 0);
                acc[i][j] = __builtin_amdgcn_mfma_f32_16x16x32_bf16(al[i], bh[j], acc[i][j], 0, 0, 0);
            }
        __syncthreads();
    }

    #pragma unroll
    for (int i = 0; i < 4; ++i) {
        #pragma unroll
        for (int q = 0; q < 4; ++q) {
            int r = rowBase + wm + i * 16 + g * 4 + q;
            if (r >= M) continue;
            #pragma unroll
            for (int j = 0; j < 4; ++j) {
                int c = colBase + wn + j * 16 + fr;
                if (c < NN)
                    C[(long)r * NN + c] = acc[i][j][q] + (bias ? bias[c] : 0.f);
            }
        }
    }
}

// ---------------- zloss: z = x @ x^T fused softplus(z) - adj*z ----------------
__global__ __launch_bounds__(256, 2)
void k_zloss(const float* __restrict__ x, const float* __restrict__ adj,
             double* __restrict__ accum)
{
    __shared__ short Ah[4][128][8], Al[4][128][8], Bh[4][128][8], Bl[4][128][8];
    __shared__ float red[256];
    const int t = threadIdx.x;
    const int rowBase = blockIdx.y * 128, colBase = blockIdx.x * 128;
    const int lane = t & 63, w = t >> 6;
    const int wm = (w >> 1) * 64, wn = (w & 1) * 64;
    const int g = lane >> 4, fr = lane & 15;

    f32x4 acc[4][4];
    #pragma unroll
    for (int i = 0; i < 4; ++i)
        #pragma unroll
        for (int j = 0; j < 4; ++j)
            acc[i][j] = (f32x4){0.f, 0.f, 0.f, 0.f};

    for (int k0 = 0; k0 < NHID; k0 += 32) {
        stage_panel(x, NHID, N_NODES, NHID, rowBase, k0, Ah, Al, t);
        stage_panel(x, NHID, N_NODES, NHID, colBase, k0, Bh, Bl, t);
        __syncthreads();
        bf16x8 ah[4], al[4], bh[4], bl[4];
        #pragma unroll
        for (int f = 0; f < 4; ++f) {
            ah[f] = *(const bf16x8*)&Ah[g][wm + f * 16 + fr][0];
            al[f] = *(const bf16x8*)&Al[g][wm + f * 16 + fr][0];
            bh[f] = *(const bf16x8*)&Bh[g][wn + f * 16 + fr][0];
            bl[f] = *(const bf16x8*)&Bl[g][wn + f * 16 + fr][0];
        }
        #pragma unroll
        for (int i = 0; i < 4; ++i)
            #pragma unroll
            for (int j = 0; j < 4; ++j) {
                acc[i][j] = __builtin_amdgcn_mfma_f32_16x16x32_bf16(ah[i], bh[j], acc[i][j], 0, 0, 0);
                acc[i][j] = __builtin_amdgcn_mfma_f32_16x16x32_bf16(ah[i], bl[j], acc[i][j], 0, 0, 0);
                acc[i][j] = __builtin_amdgcn_mfma_f32_16x16x32_bf16(al[i], bh[j], acc[i][j], 0, 0, 0);
            }
        __syncthreads();
    }

    float local = 0.f;
    #pragma unroll
    for (int i = 0; i < 4; ++i) {
        #pragma unroll
        for (int q = 0; q < 4; ++q) {
            int r = rowBase + wm + i * 16 + g * 4 + q;
            if (r >= N_NODES) continue;
            #pragma unroll
            for (int j = 0; j < 4; ++j) {
                int c = colBase + wn + j * 16 + fr;
                if (c >= N_NODES) continue;
                float z  = acc[i][j][q];
                float sp = fmaxf(z, 0.f) + log1pf(expf(-fabsf(z)));
                local += sp - adj[(long)r * N_NODES + c] * z;
            }
        }
    }
    red[t] = local;
    __syncthreads();
    for (int sft = 128; sft > 0; sft >>= 1) {
        if (t < sft) red[t] += red[t + sft];
        __syncthreads();
    }
    if (t == 0) atomicAdd(accum, (double)red[0]);
}

// ---------------- SpMM gather + bias + residual/relu ----------------
__global__ void k_spmm(const float* __restrict__ y, const float* __restrict__ xold,
                       const int* __restrict__ rowptr, const int* __restrict__ csrc,
                       const float* __restrict__ cw, const float* __restrict__ bias,
                       int do_relu, float* __restrict__ xnew)
{
    const int n  = blockIdx.x;
    const int c0 = threadIdx.x << 2;
    float4 s = make_float4(0.f, 0.f, 0.f, 0.f);
    const int beg = rowptr[n], end = rowptr[n + 1];
    for (int e = beg; e < end; ++e) {
        const int   sn = csrc[e];
        const float w  = cw[e];
        const float4 yv = *reinterpret_cast<const float4*>(y + (long)sn * NHID + c0);
        s.x = fmaf(w, yv.x, s.x);
        s.y = fmaf(w, yv.y, s.y);
        s.z = fmaf(w, yv.z, s.z);
        s.w = fmaf(w, yv.w, s.w);
    }
    const float4 bv = *reinterpret_cast<const float4*>(bias + c0);
    float4 o;
    if (do_relu) {
        o.x = fmaxf(s.x + bv.x, 0.f);
        o.y = fmaxf(s.y + bv.y, 0.f);
        o.z = fmaxf(s.z + bv.z, 0.f);
        o.w = fmaxf(s.w + bv.w, 0.f);
    } else {
        const float4 xv = *reinterpret_cast<const float4*>(xold + (long)n * NHID + c0);
        o.x = xv.x + s.x + bv.x;
        o.y = xv.y + s.y + bv.y;
        o.z = xv.z + s.z + bv.z;
        o.w = xv.w + s.w + bv.w;
    }
    *reinterpret_cast<float4*>(xnew + (long)n * NHID + c0) = o;
}

// ---------------- recon loss ----------------
__global__ void k_recon(const float* __restrict__ r0, const float* __restrict__ X0,
                        double* __restrict__ accum)
{
    const int row = blockIdx.x;
    const int t = threadIdx.x;   // 256
    float dot = 0.f, nr = 0.f, nf = 0.f;
    for (int c = t; c < F0; c += 256) {
        float a = r0[(long)row * F0 + c];
        float b = X0[(long)row * F0 + c];
        dot = fmaf(a, b, dot);
        nr  = fmaf(a, a, nr);
        nf  = fmaf(b, b, nf);
    }
    #pragma unroll
    for (int o = 32; o > 0; o >>= 1) {
        dot += __shfl_down(dot, o);
        nr  += __shfl_down(nr, o);
        nf  += __shfl_down(nf, o);
    }
    __shared__ float sd[3][4];
    const int lane = t & 63, wid = t >> 6;
    if (lane == 0) { sd[0][wid] = dot; sd[1][wid] = nr; sd[2][wid] = nf; }
    __syncthreads();
    if (t == 0) {
        float d = sd[0][0] + sd[0][1] + sd[0][2] + sd[0][3];
        float a = sd[1][0] + sd[1][1] + sd[1][2] + sd[1][3];
        float b = sd[2][0] + sd[2][1] + sd[2][2] + sd[2][3];
        float cosv = d / (fmaxf(sqrtf(a), 1e-12f) * fmaxf(sqrtf(b), 1e-12f));
        float v = 1.f - cosv;
        atomicAdd(accum + 1, (double)(v * v * v));
    }
}

__global__ void k_final(const double* __restrict__ accum, float* __restrict__ out)
{
    if (threadIdx.x == 0) {
        out[45082958] = (float)(accum[0] / ((double)N_NODES * (double)N_NODES));
        out[45082959] = (float)(accum[1] / (double)S0);
    }
}

extern "C" void kernel_launch(void* const* d_in, const int* in_sizes, int n_in,
                              void* d_out, int out_size, void* d_ws, size_t ws_size,
                              hipStream_t stream)
{
    const float* X0  = (const float*)d_in[0];
    const float* X1  = (const float*)d_in[1];
    const float* X2  = (const float*)d_in[2];
    const int*   src = (const int*)d_in[3];
    const int*   dst = (const int*)d_in[4];
    const float* ew  = (const float*)d_in[5];
    const float* adj = (const float*)d_in[6];
    const float* fcW[3]  = {(const float*)d_in[7],  (const float*)d_in[9],  (const float*)d_in[11]};
    const float* fcB[3]  = {(const float*)d_in[8],  (const float*)d_in[10], (const float*)d_in[12]};
    const float* encW = (const float*)d_in[13];
    const float* encB = (const float*)d_in[14];
    const float* decW = (const float*)d_in[15];
    const float* decB = (const float*)d_in[16];
    const float* outW[3] = {(const float*)d_in[17], (const float*)d_in[19], (const float*)d_in[21]};
    const float* outB[3] = {(const float*)d_in[18], (const float*)d_in[20], (const float*)d_in[22]};
    float* out = (float*)d_out;

    char* ws = (char*)d_ws;
    size_t off = 0;
    double* accum = (double*)(ws); off += 16;
    const size_t XB = (size_t)N_NODES * NHID * sizeof(float);
    float* xbuf = (float*)(ws + off); off += XB;
    float* ybuf = (float*)(ws + off); off += XB;   // also reused for fcT / outT
    float* xalt = (float*)(ws + off); off += XB;
    float* wT   = (float*)(ws + off); off += (size_t)8 * NHID * NHID * sizeof(float);
    int* indeg  = (int*)(ws + off);   off += ((size_t)N_NODES * 4 + 15) & ~(size_t)15;
    int* rowptr = (int*)(ws + off);   off += ((size_t)(N_NODES + 1) * 4 + 15) & ~(size_t)15;
    int* cursor = (int*)(ws + off);   off += ((size_t)N_NODES * 4 + 15) & ~(size_t)15;
    int* csrc   = (int*)(ws + off);   off += (size_t)EDGES * 4;
    float* cw   = (float*)(ws + off); off += (size_t)EDGES * 4;

    const int FD[3] = {F0, F1, F2};
    const int SD[3] = {S0, S1, S2};
    const float* XD[3] = {X0, X1, X2};

    // ---- CSR build ----
    k_init<<<dim3((N_NODES + 255) / 256), dim3(256), 0, stream>>>(accum, indeg, cursor);
    k_count<<<dim3((EDGES + 255) / 256), dim3(256), 0, stream>>>(dst, indeg);
    k_scan<<<dim3(1), dim3(256), 0, stream>>>(indeg, rowptr);
    k_fill<<<dim3((EDGES + 255) / 256), dim3(256), 0, stream>>>(src, dst, ew, rowptr, cursor, csrc, cw);

    auto tgrid = [](int R, int C) { return dim3((unsigned)((C + 31) / 32), (unsigned)((R + 31) / 32)); };
    auto ggrid = [](int m, int nn) { return dim3((unsigned)((nn + 127) / 128), (unsigned)((m + 127) / 128)); };

    // ---- transpose fc weights into ybuf (idle until layer loop) ----
    {
        float* p = ybuf;
        for (int i = 0; i < 3; ++i) {
            k_transpose<<<tgrid(FD[i], NHID), dim3(32, 8), 0, stream>>>(fcW[i], p, FD[i], NHID);
            p += (size_t)NHID * FD[i];
        }
    }
    // ---- transpose enc/dec weights into wT ----
    for (int i = 0; i < 4; ++i)
        k_transpose<<<tgrid(NHID, NHID), dim3(32, 8), 0, stream>>>(
            encW + (size_t)i * NHID * NHID, wT + (size_t)i * NHID * NHID, NHID, NHID);
    for (int i = 0; i < 4; ++i)
        k_transpose<<<tgrid(NHID, NHID), dim3(32, 8), 0, stream>>>(
            decW + (size_t)i * NHID * NHID, wT + (size_t)(4 + i) * NHID * NHID, NHID, NHID);

    // ---- input FCs -> xbuf (concatenated rows) ----
    {
        float* p = ybuf;
        float* xo = xbuf;
        for (int i = 0; i < 3; ++i) {
            k_gemm_bt<<<ggrid(SD[i], NHID), dim3(256), 0, stream>>>(
                XD[i], p, fcB[i], xo, SD[i], FD[i], NHID);
            p  += (size_t)NHID * FD[i];
            xo += (size_t)SD[i] * NHID;
        }
    }

    // ---- 8 GNN layers ----
    float* x  = xbuf;
    float* xn = xalt;
    for (int phase = 0; phase < 2; ++phase) {
        const float* B = phase ? decB : encB;
        for (int i = 0; i < 4; ++i) {
            const float* Wt = wT + (size_t)(phase * 4 + i) * NHID * NHID;
            k_gemm_bt<<<ggrid(N_NODES, NHID), dim3(256), 0, stream>>>(
                x, Wt, nullptr, ybuf, N_NODES, NHID, NHID);
            k_spmm<<<dim3(N_NODES), dim3(128), 0, stream>>>(
                ybuf, x, rowptr, csrc, cw, B + (size_t)i * NHID, (i == 0) ? 1 : 0, xn);
            float* tmp = x; x = xn; xn = tmp;
        }
    }
    // after 8 swaps x == xbuf; ybuf is now free again

    // ---- transpose out weights into ybuf ----
    {
        float* p = ybuf;
        for (int i = 0; i < 3; ++i) {
            k_transpose<<<tgrid(NHID, FD[i]), dim3(32, 8), 0, stream>>>(outW[i], p, NHID, FD[i]);
            p += (size_t)NHID * FD[i];
        }
    }

    // ---- output projections ----
    {
        float* p = ybuf;
        float* oo = out;
        const float* xs = x;
        for (int i = 0; i < 3; ++i) {
            k_gemm_bt<<<ggrid(SD[i], FD[i]), dim3(256), 0, stream>>>(
                xs, p, outB[i], oo, SD[i], NHID, FD[i]);
            p  += (size_t)NHID * FD[i];
            oo += (size_t)SD[i] * FD[i];
            xs += (size_t)SD[i] * NHID;
        }
    }

    // ---- losses ----
    k_zloss<<<dim3((N_NODES + 127) / 128, (N_NODES + 127) / 128), dim3(256), 0, stream>>>(x, adj, accum);
    k_recon<<<dim3(S0), dim3(256), 0, stream>>>(out, X0, accum);
    k_final<<<dim3(1), dim3(64), 0, stream>>>(accum, out);
}

// Round 3
// 4738.555 us; speedup vs baseline: 2.1224x; 1.1113x over previous
//
#include <hip/hip_runtime.h>
#include <math.h>

#define N_NODES 11616
#define NHID    512
#define EDGES   371712
#define S0 4278
#define S1 2081
#define S2 5257
#define F0 3066
#define F1 2081
#define F2 5257
#define NBLK 91   // ceil(11616/128)

typedef __attribute__((ext_vector_type(8))) short bf16x8;
typedef __attribute__((ext_vector_type(4))) float f32x4;

#define LDS_SWZ(m, g) ((m) ^ ((g) << 1))

// ---------------- init ----------------
__global__ void k_init(double* __restrict__ accum, int* __restrict__ indeg,
                       int* __restrict__ cursor)
{
    int i = blockIdx.x * blockDim.x + threadIdx.x;
    if (i < 2) accum[i] = 0.0;
    if (i < N_NODES) { indeg[i] = 0; cursor[i] = 0; }
}

// ---------------- CSR build ----------------
__global__ void k_count(const int* __restrict__ dst, int* __restrict__ indeg)
{
    int e = blockIdx.x * blockDim.x + threadIdx.x;
    if (e < EDGES) atomicAdd(&indeg[dst[e]], 1);
}

__global__ void k_scan(const int* __restrict__ indeg, int* __restrict__ rowptr)
{
    __shared__ int part[256];
    const int t = threadIdx.x;
    const int chunk = (N_NODES + 255) / 256;
    const int base = t * chunk;
    int s = 0;
    for (int i = 0; i < chunk; ++i) {
        int idx = base + i;
        if (idx < N_NODES) s += indeg[idx];
    }
    part[t] = s;
    __syncthreads();
    if (t == 0) for (int i = 1; i < 256; ++i) part[i] += part[i - 1];
    __syncthreads();
    int run = (t == 0) ? 0 : part[t - 1];
    for (int i = 0; i < chunk; ++i) {
        int idx = base + i;
        if (idx < N_NODES) { rowptr[idx] = run; run += indeg[idx]; }
    }
    if (t == 0) rowptr[N_NODES] = part[255];
}

__global__ void k_fill(const int* __restrict__ src, const int* __restrict__ dst,
                       const float* __restrict__ ew, const int* __restrict__ rowptr,
                       int* __restrict__ cursor, int* __restrict__ csrc,
                       float* __restrict__ cw)
{
    int e = blockIdx.x * blockDim.x + threadIdx.x;
    if (e >= EDGES) return;
    int d = dst[e];
    int pos = rowptr[d] + atomicAdd(&cursor[d], 1);
    csrc[pos] = src[e];
    cw[pos]   = ew[e];
}

// ---------------- bf16 hi/lo split ----------------
__device__ __forceinline__ void split_bf16(float f, short& hi, short& lo)
{
    unsigned u  = __float_as_uint(f);
    unsigned hr = (u + 0x7FFFu + ((u >> 16) & 1u)) & 0xFFFF0000u;
    float    fh = __uint_as_float(hr);
    float    fl = f - fh;
    unsigned ul = __float_as_uint(fl);
    unsigned lr = ul + 0x7FFFu + ((ul >> 16) & 1u);
    hi = (short)(hr >> 16);
    lo = (short)(lr >> 16);
}

// elementwise split: in (n4 float4s) -> hi/lo bf16 arrays
__global__ void k_split(const float* __restrict__ in, short* __restrict__ oh,
                        short* __restrict__ ol, int n4)
{
    int i = blockIdx.x * blockDim.x + threadIdx.x;
    if (i >= n4) return;
    float4 v = reinterpret_cast<const float4*>(in)[i];
    short4 h, l;
    split_bf16(v.x, h.x, l.x);
    split_bf16(v.y, h.y, l.y);
    split_bf16(v.z, h.z, l.z);
    split_bf16(v.w, h.w, l.w);
    reinterpret_cast<short4*>(oh)[i] = h;
    reinterpret_cast<short4*>(ol)[i] = l;
}

// transpose + split: in[R][C] fp32 -> oh/ol[C][Rpad] bf16 (zero-padded cols R..Rpad)
__global__ void k_tsplit(const float* __restrict__ in, short* __restrict__ oh,
                         short* __restrict__ ol, int R, int C, int Rpad)
{
    __shared__ float tile[32][33];
    const int cb = blockIdx.x * 32, rb = blockIdx.y * 32;
    const int tx = threadIdx.x, ty = threadIdx.y;   // 32 x 8
    #pragma unroll
    for (int i = ty; i < 32; i += 8) {
        int r = rb + i, c = cb + tx;
        tile[i][tx] = (r < R && c < C) ? in[(long)r * C + c] : 0.f;
    }
    __syncthreads();
    #pragma unroll
    for (int i = ty; i < 32; i += 8) {
        int row = cb + i, col = rb + tx;
        if (row < C && col < Rpad) {
            short h, l;
            split_bf16(tile[tx][i], h, l);
            oh[(long)row * Rpad + col] = h;
            ol[(long)row * Rpad + col] = l;
        }
    }
}

__device__ __forceinline__ bf16x8 bf16x8_zero()
{
    bf16x8 z;
    #pragma unroll
    for (int j = 0; j < 8; ++j) z[j] = 0;
    return z;
}

// ---------------- GEMM: both operands pre-split bf16 ----------------
// C[M][NN] = A @ B^T (+bias), A rows via Ah/Al [M][ldk], B rows via Bh/Bl [NN][ldk]
__global__ __launch_bounds__(256, 2)
void k_gemm_bb(const short* __restrict__ Agh, const short* __restrict__ Agl,
               const short* __restrict__ Bgh, const short* __restrict__ Bgl,
               const float* __restrict__ bias, float* __restrict__ C,
               int M, int NN, int Kpad, int ldk)
{
    __shared__ short Ah[4][128][8], Al[4][128][8], Bh[4][128][8], Bl[4][128][8];
    const int t = threadIdx.x;
    const int rowBase = blockIdx.y * 128, colBase = blockIdx.x * 128;
    const int lane = t & 63, w = t >> 6;
    const int wm = (w >> 1) * 64, wn = (w & 1) * 64;
    const int kg = lane >> 4, fr = lane & 15;
    const int g = t & 3, mA = t >> 2, mB = mA + 64;

    f32x4 acc[4][4];
    #pragma unroll
    for (int i = 0; i < 4; ++i)
        #pragma unroll
        for (int j = 0; j < 4; ++j)
            acc[i][j] = (f32x4){0.f, 0.f, 0.f, 0.f};

    bf16x8 rAh0, rAh1, rAl0, rAl1, rBh0, rBh1, rBl0, rBl1;
    const int ko = g * 8;
    int r0 = rowBase + mA, r1 = rowBase + mB;
    int c0 = colBase + mA, c1 = colBase + mB;

#define LOADT(k0)                                                                     \
    {                                                                                 \
        long kb = (long)(k0) + ko;                                                    \
        rAh0 = (r0 < M)  ? *(const bf16x8*)(Agh + (long)r0 * ldk + kb) : bf16x8_zero(); \
        rAl0 = (r0 < M)  ? *(const bf16x8*)(Agl + (long)r0 * ldk + kb) : bf16x8_zero(); \
        rAh1 = (r1 < M)  ? *(const bf16x8*)(Agh + (long)r1 * ldk + kb) : bf16x8_zero(); \
        rAl1 = (r1 < M)  ? *(const bf16x8*)(Agl + (long)r1 * ldk + kb) : bf16x8_zero(); \
        rBh0 = (c0 < NN) ? *(const bf16x8*)(Bgh + (long)c0 * ldk + kb) : bf16x8_zero(); \
        rBl0 = (c0 < NN) ? *(const bf16x8*)(Bgl + (long)c0 * ldk + kb) : bf16x8_zero(); \
        rBh1 = (c1 < NN) ? *(const bf16x8*)(Bgh + (long)c1 * ldk + kb) : bf16x8_zero(); \
        rBl1 = (c1 < NN) ? *(const bf16x8*)(Bgl + (long)c1 * ldk + kb) : bf16x8_zero(); \
    }

#define WRITET()                                                  \
    {                                                             \
        *(bf16x8*)&Ah[g][LDS_SWZ(mA, g)][0] = rAh0;               \
        *(bf16x8*)&Al[g][LDS_SWZ(mA, g)][0] = rAl0;               \
        *(bf16x8*)&Ah[g][LDS_SWZ(mB, g)][0] = rAh1;               \
        *(bf16x8*)&Al[g][LDS_SWZ(mB, g)][0] = rAl1;               \
        *(bf16x8*)&Bh[g][LDS_SWZ(mA, g)][0] = rBh0;               \
        *(bf16x8*)&Bl[g][LDS_SWZ(mA, g)][0] = rBl0;               \
        *(bf16x8*)&Bh[g][LDS_SWZ(mB, g)][0] = rBh1;               \
        *(bf16x8*)&Bl[g][LDS_SWZ(mB, g)][0] = rBl1;               \
    }

    LOADT(0);
    const int nkt = Kpad >> 5;
    for (int kt = 0; kt < nkt; ++kt) {
        WRITET();
        __syncthreads();
        if (kt + 1 < nkt) LOADT((kt + 1) << 5);
        bf16x8 ah[4], al[4], bh[4], bl[4];
        #pragma unroll
        for (int f = 0; f < 4; ++f) {
            int ra = wm + f * 16 + fr, rb = wn + f * 16 + fr;
            ah[f] = *(const bf16x8*)&Ah[kg][LDS_SWZ(ra, kg)][0];
            al[f] = *(const bf16x8*)&Al[kg][LDS_SWZ(ra, kg)][0];
            bh[f] = *(const bf16x8*)&Bh[kg][LDS_SWZ(rb, kg)][0];
            bl[f] = *(const bf16x8*)&Bl[kg][LDS_SWZ(rb, kg)][0];
        }
        #pragma unroll
        for (int i = 0; i < 4; ++i)
            #pragma unroll
            for (int j = 0; j < 4; ++j) {
                acc[i][j] = __builtin_amdgcn_mfma_f32_16x16x32_bf16(ah[i], bh[j], acc[i][j], 0, 0, 0);
                acc[i][j] = __builtin_amdgcn_mfma_f32_16x16x32_bf16(ah[i], bl[j], acc[i][j], 0, 0, 0);
                acc[i][j] = __builtin_amdgcn_mfma_f32_16x16x32_bf16(al[i], bh[j], acc[i][j], 0, 0, 0);
            }
        __syncthreads();
    }
#undef LOADT
#undef WRITET

    #pragma unroll
    for (int i = 0; i < 4; ++i) {
        #pragma unroll
        for (int q = 0; q < 4; ++q) {
            int r = rowBase + wm + i * 16 + kg * 4 + q;
            if (r >= M) continue;
            #pragma unroll
            for (int j = 0; j < 4; ++j) {
                int c = colBase + wn + j * 16 + fr;
                if (c < NN)
                    C[(long)r * NN + c] = acc[i][j][q] + (bias ? bias[c] : 0.f);
            }
        }
    }
}

// ---------------- GEMM: A fp32 (split on the fly), B pre-split ----------------
__global__ __launch_bounds__(256, 2)
void k_gemm_fa(const float* __restrict__ A,
               const short* __restrict__ Bgh, const short* __restrict__ Bgl,
               const float* __restrict__ bias, float* __restrict__ C,
               int M, int NN, int K, int Kpad, int ldkB)
{
    __shared__ short Ah[4][128][8], Al[4][128][8], Bh[4][128][8], Bl[4][128][8];
    const int t = threadIdx.x;
    const int rowBase = blockIdx.y * 128, colBase = blockIdx.x * 128;
    const int lane = t & 63, w = t >> 6;
    const int wm = (w >> 1) * 64, wn = (w & 1) * 64;
    const int kg = lane >> 4, fr = lane & 15;
    const int g = t & 3, mA = t >> 2, mB = mA + 64;

    f32x4 acc[4][4];
    #pragma unroll
    for (int i = 0; i < 4; ++i)
        #pragma unroll
        for (int j = 0; j < 4; ++j)
            acc[i][j] = (f32x4){0.f, 0.f, 0.f, 0.f};

    const int ko = g * 8;
    int r0 = rowBase + mA, r1 = rowBase + mB;
    int c0 = colBase + mA, c1 = colBase + mB;

    const int nkt = Kpad >> 5;
    for (int kt = 0; kt < nkt; ++kt) {
        const int k0 = kt << 5;
        // A: fp32 + split
        #pragma unroll
        for (int half = 0; half < 2; ++half) {
            int row = half ? r1 : r0;
            int m   = half ? mB : mA;
            bf16x8 hv = bf16x8_zero(), lv = bf16x8_zero();
            if (row < M) {
                const float* rp = A + (long)row * K + k0 + ko;
                #pragma unroll
                for (int j = 0; j < 8; ++j) {
                    int k = k0 + ko + j;
                    float f = (k < K) ? rp[j] : 0.f;
                    short h, l;
                    split_bf16(f, h, l);
                    hv[j] = h; lv[j] = l;
                }
            }
            *(bf16x8*)&Ah[g][LDS_SWZ(m, g)][0] = hv;
            *(bf16x8*)&Al[g][LDS_SWZ(m, g)][0] = lv;
        }
        // B: bf16 pre-split (zero-padded to Kpad)
        {
            long kb = (long)k0 + ko;
            bf16x8 b0h = (c0 < NN) ? *(const bf16x8*)(Bgh + (long)c0 * ldkB + kb) : bf16x8_zero();
            bf16x8 b0l = (c0 < NN) ? *(const bf16x8*)(Bgl + (long)c0 * ldkB + kb) : bf16x8_zero();
            bf16x8 b1h = (c1 < NN) ? *(const bf16x8*)(Bgh + (long)c1 * ldkB + kb) : bf16x8_zero();
            bf16x8 b1l = (c1 < NN) ? *(const bf16x8*)(Bgl + (long)c1 * ldkB + kb) : bf16x8_zero();
            *(bf16x8*)&Bh[g][LDS_SWZ(mA, g)][0] = b0h;
            *(bf16x8*)&Bl[g][LDS_SWZ(mA, g)][0] = b0l;
            *(bf16x8*)&Bh[g][LDS_SWZ(mB, g)][0] = b1h;
            *(bf16x8*)&Bl[g][LDS_SWZ(mB, g)][0] = b1l;
        }
        __syncthreads();
        bf16x8 ah[4], al[4], bh[4], bl[4];
        #pragma unroll
        for (int f = 0; f < 4; ++f) {
            int ra = wm + f * 16 + fr, rb = wn + f * 16 + fr;
            ah[f] = *(const bf16x8*)&Ah[kg][LDS_SWZ(ra, kg)][0];
            al[f] = *(const bf16x8*)&Al[kg][LDS_SWZ(ra, kg)][0];
            bh[f] = *(const bf16x8*)&Bh[kg][LDS_SWZ(rb, kg)][0];
            bl[f] = *(const bf16x8*)&Bl[kg][LDS_SWZ(rb, kg)][0];
        }
        #pragma unroll
        for (int i = 0; i < 4; ++i)
            #pragma unroll
            for (int j = 0; j < 4; ++j) {
                acc[i][j] = __builtin_amdgcn_mfma_f32_16x16x32_bf16(ah[i], bh[j], acc[i][j], 0, 0, 0);
                acc[i][j] = __builtin_amdgcn_mfma_f32_16x16x32_bf16(ah[i], bl[j], acc[i][j], 0, 0, 0);
                acc[i][j] = __builtin_amdgcn_mfma_f32_16x16x32_bf16(al[i], bh[j], acc[i][j], 0, 0, 0);
            }
        __syncthreads();
    }

    #pragma unroll
    for (int i = 0; i < 4; ++i) {
        #pragma unroll
        for (int q = 0; q < 4; ++q) {
            int r = rowBase + wm + i * 16 + kg * 4 + q;
            if (r >= M) continue;
            #pragma unroll
            for (int j = 0; j < 4; ++j) {
                int c = colBase + wn + j * 16 + fr;
                if (c < NN)
                    C[(long)r * NN + c] = acc[i][j][q] + (bias ? bias[c] : 0.f);
            }
        }
    }
}

// ---------------- zloss: upper-triangle blocks of z = x x^T, fused loss ----------------
__global__ __launch_bounds__(256, 2)
void k_zloss(const short* __restrict__ xh, const short* __restrict__ xl,
             const float* __restrict__ adj, double* __restrict__ accum)
{
    __shared__ short Ah[4][128][8], Al[4][128][8], Bh[4][128][8], Bl[4][128][8];
    __shared__ float red[256];
    const int t = threadIdx.x;

    // map linear block -> upper-triangle (R,C), C >= R
    int b = blockIdx.x, R = 0;
    while (b >= NBLK - R) { b -= NBLK - R; ++R; }
    const int Cb = R + b;
    const int rowBase = R * 128, colBase = Cb * 128;
    const int diag = (Cb == R);

    const int lane = t & 63, w = t >> 6;
    const int wm = (w >> 1) * 64, wn = (w & 1) * 64;
    const int kg = lane >> 4, fr = lane & 15;
    const int g = t & 3, mA = t >> 2, mB = mA + 64;

    f32x4 acc[4][4];
    #pragma unroll
    for (int i = 0; i < 4; ++i)
        #pragma unroll
        for (int j = 0; j < 4; ++j)
            acc[i][j] = (f32x4){0.f, 0.f, 0.f, 0.f};

    bf16x8 rAh0, rAh1, rAl0, rAl1, rBh0, rBh1, rBl0, rBl1;
    const int ko = g * 8;
    int r0 = rowBase + mA, r1 = rowBase + mB;
    int c0 = colBase + mA, c1 = colBase + mB;

#define LOADT(k0)                                                                          \
    {                                                                                      \
        long kb = (long)(k0) + ko;                                                         \
        rAh0 = (r0 < N_NODES) ? *(const bf16x8*)(xh + (long)r0 * NHID + kb) : bf16x8_zero(); \
        rAl0 = (r0 < N_NODES) ? *(const bf16x8*)(xl + (long)r0 * NHID + kb) : bf16x8_zero(); \
        rAh1 = (r1 < N_NODES) ? *(const bf16x8*)(xh + (long)r1 * NHID + kb) : bf16x8_zero(); \
        rAl1 = (r1 < N_NODES) ? *(const bf16x8*)(xl + (long)r1 * NHID + kb) : bf16x8_zero(); \
        rBh0 = (c0 < N_NODES) ? *(const bf16x8*)(xh + (long)c0 * NHID + kb) : bf16x8_zero(); \
        rBl0 = (c0 < N_NODES) ? *(const bf16x8*)(xl + (long)c0 * NHID + kb) : bf16x8_zero(); \
        rBh1 = (c1 < N_NODES) ? *(const bf16x8*)(xh + (long)c1 * NHID + kb) : bf16x8_zero(); \
        rBl1 = (c1 < N_NODES) ? *(const bf16x8*)(xl + (long)c1 * NHID + kb) : bf16x8_zero(); \
    }
#define WRITET()                                                  \
    {                                                             \
        *(bf16x8*)&Ah[g][LDS_SWZ(mA, g)][0] = rAh0;               \
        *(bf16x8*)&Al[g][LDS_SWZ(mA, g)][0] = rAl0;               \
        *(bf16x8*)&Ah[g][LDS_SWZ(mB, g)][0] = rAh1;               \
        *(bf16x8*)&Al[g][LDS_SWZ(mB, g)][0] = rAl1;               \
        *(bf16x8*)&Bh[g][LDS_SWZ(mA, g)][0] = rBh0;               \
        *(bf16x8*)&Bl[g][LDS_SWZ(mA, g)][0] = rBl0;               \
        *(bf16x8*)&Bh[g][LDS_SWZ(mB, g)][0] = rBh1;               \
        *(bf16x8*)&Bl[g][LDS_SWZ(mB, g)][0] = rBl1;               \
    }

    LOADT(0);
    for (int kt = 0; kt < NHID / 32; ++kt) {
        WRITET();
        __syncthreads();
        if (kt + 1 < NHID / 32) LOADT((kt + 1) << 5);
        bf16x8 ah[4], al[4], bh[4], bl[4];
        #pragma unroll
        for (int f = 0; f < 4; ++f) {
            int ra = wm + f * 16 + fr, rb = wn + f * 16 + fr;
            ah[f] = *(const bf16x8*)&Ah[kg][LDS_SWZ(ra, kg)][0];
            al[f] = *(const bf16x8*)&Al[kg][LDS_SWZ(ra, kg)][0];
            bh[f] = *(const bf16x8*)&Bh[kg][LDS_SWZ(rb, kg)][0];
            bl[f] = *(const bf16x8*)&Bl[kg][LDS_SWZ(rb, kg)][0];
        }
        #pragma unroll
        for (int i = 0; i < 4; ++i)
            #pragma unroll
            for (int j = 0; j < 4; ++j) {
                acc[i][j] = __builtin_amdgcn_mfma_f32_16x16x32_bf16(ah[i], bh[j], acc[i][j], 0, 0, 0);
                acc[i][j] = __builtin_amdgcn_mfma_f32_16x16x32_bf16(ah[i], bl[j], acc[i][j], 0, 0, 0);
                acc[i][j] = __builtin_amdgcn_mfma_f32_16x16x32_bf16(al[i], bh[j], acc[i][j], 0, 0, 0);
            }
        __syncthreads();
    }
#undef LOADT
#undef WRITET

    float local = 0.f;
    #pragma unroll
    for (int i = 0; i < 4; ++i) {
        #pragma unroll
        for (int q = 0; q < 4; ++q) {
            int r = rowBase + wm + i * 16 + kg * 4 + q;
            if (r >= N_NODES) continue;
            #pragma unroll
            for (int j = 0; j < 4; ++j) {
                int c = colBase + wn + j * 16 + fr;
                if (c >= N_NODES) continue;
                float z  = acc[i][j][q];
                float sp = fmaxf(z, 0.f) + log1pf(expf(-fabsf(z)));
                if (diag) {
                    local += sp - adj[(long)r * N_NODES + c] * z;
                } else {
                    float a1 = adj[(long)r * N_NODES + c];
                    float a2 = adj[(long)c * N_NODES + r];
                    local += 2.f * sp - (a1 + a2) * z;
                }
            }
        }
    }
    red[t] = local;
    __syncthreads();
    for (int sft = 128; sft > 0; sft >>= 1) {
        if (t < sft) red[t] += red[t + sft];
        __syncthreads();
    }
    if (t == 0) atomicAdd(accum, (double)red[0]);
}

// ---------------- SpMM, channel-chunked (64 ch/chunk, chunk = blockIdx & 7) ----------------
__global__ void k_spmm(const float* __restrict__ y, const float* __restrict__ xold,
                       const int* __restrict__ rowptr, const int* __restrict__ csrc,
                       const float* __restrict__ cw, const float* __restrict__ bias,
                       int do_relu, float* __restrict__ xnew)
{
    const int chunk = blockIdx.x & 7;
    const int nb    = blockIdx.x >> 3;
    const int wv    = threadIdx.x >> 6;
    const int lane  = threadIdx.x & 63;
    const int n     = nb * 4 + wv;          // 2904*4 == 11616 exactly
    const int c     = chunk * 64 + lane;
    float acc = 0.f;
    const int beg = rowptr[n], end = rowptr[n + 1];
    for (int e = beg; e < end; ++e) {
        int   sn = __builtin_nontemporal_load(csrc + e);
        float wt = __builtin_nontemporal_load(cw + e);
        acc = fmaf(wt, y[(long)sn * NHID + c], acc);
    }
    float o = acc + bias[c];
    if (do_relu) o = fmaxf(o, 0.f);
    else         o += xold[(long)n * NHID + c];
    xnew[(long)n * NHID + c] = o;
}

// ---------------- recon loss ----------------
__global__ void k_recon(const float* __restrict__ r0, const float* __restrict__ X0,
                        double* __restrict__ accum)
{
    const int row = blockIdx.x;
    const int t = threadIdx.x;   // 256
    float dot = 0.f, nr = 0.f, nf = 0.f;
    for (int c = t; c < F0; c += 256) {
        float a = r0[(long)row * F0 + c];
        float b = X0[(long)row * F0 + c];
        dot = fmaf(a, b, dot);
        nr  = fmaf(a, a, nr);
        nf  = fmaf(b, b, nf);
    }
    #pragma unroll
    for (int o = 32; o > 0; o >>= 1) {
        dot += __shfl_down(dot, o);
        nr  += __shfl_down(nr, o);
        nf  += __shfl_down(nf, o);
    }
    __shared__ float sd[3][4];
    const int lane = t & 63, wid = t >> 6;
    if (lane == 0) { sd[0][wid] = dot; sd[1][wid] = nr; sd[2][wid] = nf; }
    __syncthreads();
    if (t == 0) {
        float d = sd[0][0] + sd[0][1] + sd[0][2] + sd[0][3];
        float a = sd[1][0] + sd[1][1] + sd[1][2] + sd[1][3];
        float b = sd[2][0] + sd[2][1] + sd[2][2] + sd[2][3];
        float cosv = d / (fmaxf(sqrtf(a), 1e-12f) * fmaxf(sqrtf(b), 1e-12f));
        float v = 1.f - cosv;
        atomicAdd(accum + 1, (double)(v * v * v));
    }
}

__global__ void k_final(const double* __restrict__ accum, float* __restrict__ out)
{
    if (threadIdx.x == 0) {
        out[45082958] = (float)(accum[0] / ((double)N_NODES * (double)N_NODES));
        out[45082959] = (float)(accum[1] / (double)S0);
    }
}

extern "C" void kernel_launch(void* const* d_in, const int* in_sizes, int n_in,
                              void* d_out, int out_size, void* d_ws, size_t ws_size,
                              hipStream_t stream)
{
    const float* X0  = (const float*)d_in[0];
    const float* X1  = (const float*)d_in[1];
    const float* X2  = (const float*)d_in[2];
    const int*   src = (const int*)d_in[3];
    const int*   dst = (const int*)d_in[4];
    const float* ew  = (const float*)d_in[5];
    const float* adj = (const float*)d_in[6];
    const float* fcW[3]  = {(const float*)d_in[7],  (const float*)d_in[9],  (const float*)d_in[11]};
    const float* fcB[3]  = {(const float*)d_in[8],  (const float*)d_in[10], (const float*)d_in[12]};
    const float* encW = (const float*)d_in[13];
    const float* encB = (const float*)d_in[14];
    const float* decW = (const float*)d_in[15];
    const float* decB = (const float*)d_in[16];
    const float* outW[3] = {(const float*)d_in[17], (const float*)d_in[19], (const float*)d_in[21]};
    const float* outB[3] = {(const float*)d_in[18], (const float*)d_in[20], (const float*)d_in[22]};
    float* out = (float*)d_out;

    const int FD[3]   = {F0, F1, F2};
    const int FPAD[3] = {(F0 + 31) & ~31, (F1 + 31) & ~31, (F2 + 31) & ~31};
    const int SD[3]   = {S0, S1, S2};
    const float* XD[3] = {X0, X1, X2};

    char* ws = (char*)d_ws;
    size_t off = 0;
    auto alloc = [&](size_t bytes) { void* p = ws + off; off += (bytes + 255) & ~(size_t)255; return p; };

    double* accum = (double*)alloc(16);
    const size_t XB = (size_t)N_NODES * NHID * sizeof(float);
    float* xbuf = (float*)alloc(XB);
    float* ybuf = (float*)alloc(XB);
    float* xalt = (float*)alloc(XB);
    short* xh   = (short*)alloc((size_t)N_NODES * NHID * 2);
    short* xl   = (short*)alloc((size_t)N_NODES * NHID * 2);
    size_t fcWel = (size_t)NHID * (FPAD[0] + FPAD[1] + FPAD[2]);
    short* fcWh = (short*)alloc(fcWel * 2);
    short* fcWl = (short*)alloc(fcWel * 2);
    short* wTh  = (short*)alloc((size_t)8 * NHID * NHID * 2);
    short* wTl  = (short*)alloc((size_t)8 * NHID * NHID * 2);
    size_t outWel = (size_t)NHID * (F0 + F1 + F2);
    short* oWh  = (short*)alloc(outWel * 2);
    short* oWl  = (short*)alloc(outWel * 2);
    int* indeg  = (int*)alloc((size_t)N_NODES * 4);
    int* rowptr = (int*)alloc((size_t)(N_NODES + 1) * 4);
    int* cursor = (int*)alloc((size_t)N_NODES * 4);
    int* csrc   = (int*)alloc((size_t)EDGES * 4);
    float* cw   = (float*)alloc((size_t)EDGES * 4);

    // ---- CSR build ----
    k_init<<<dim3((N_NODES + 255) / 256), dim3(256), 0, stream>>>(accum, indeg, cursor);
    k_count<<<dim3((EDGES + 255) / 256), dim3(256), 0, stream>>>(dst, indeg);
    k_scan<<<dim3(1), dim3(256), 0, stream>>>(indeg, rowptr);
    k_fill<<<dim3((EDGES + 255) / 256), dim3(256), 0, stream>>>(src, dst, ew, rowptr, cursor, csrc, cw);

    auto tgrid = [](int C, int Rpad) { return dim3((unsigned)((C + 31) / 32), (unsigned)((Rpad + 31) / 32)); };
    auto ggrid = [](int m, int nn) { return dim3((unsigned)((nn + 127) / 128), (unsigned)((m + 127) / 128)); };

    // ---- weight transpose+split ----
    {
        short *ph = fcWh, *pl = fcWl;
        for (int i = 0; i < 3; ++i) {
            k_tsplit<<<tgrid(NHID, FPAD[i]), dim3(32, 8), 0, stream>>>(fcW[i], ph, pl, FD[i], NHID, FPAD[i]);
            ph += (size_t)NHID * FPAD[i]; pl += (size_t)NHID * FPAD[i];
        }
    }
    for (int i = 0; i < 4; ++i) {
        k_tsplit<<<tgrid(NHID, NHID), dim3(32, 8), 0, stream>>>(
            encW + (size_t)i * NHID * NHID, wTh + (size_t)i * NHID * NHID,
            wTl + (size_t)i * NHID * NHID, NHID, NHID, NHID);
        k_tsplit<<<tgrid(NHID, NHID), dim3(32, 8), 0, stream>>>(
            decW + (size_t)i * NHID * NHID, wTh + (size_t)(4 + i) * NHID * NHID,
            wTl + (size_t)(4 + i) * NHID * NHID, NHID, NHID, NHID);
    }
    {
        short *ph = oWh, *pl = oWl;
        for (int i = 0; i < 3; ++i) {
            k_tsplit<<<tgrid(FD[i], NHID), dim3(32, 8), 0, stream>>>(outW[i], ph, pl, NHID, FD[i], NHID);
            ph += (size_t)FD[i] * NHID; pl += (size_t)FD[i] * NHID;
        }
    }

    // ---- input FCs -> xbuf ----
    {
        short *ph = fcWh, *pl = fcWl;
        float* xo = xbuf;
        for (int i = 0; i < 3; ++i) {
            k_gemm_fa<<<ggrid(SD[i], NHID), dim3(256), 0, stream>>>(
                XD[i], ph, pl, fcB[i], xo, SD[i], NHID, FD[i], FPAD[i], FPAD[i]);
            ph += (size_t)NHID * FPAD[i]; pl += (size_t)NHID * FPAD[i];
            xo += (size_t)SD[i] * NHID;
        }
    }

    // ---- 8 GNN layers ----
    const int n4 = N_NODES * NHID / 4;
    float* x  = xbuf;
    float* xn = xalt;
    for (int phase = 0; phase < 2; ++phase) {
        const float* B = phase ? decB : encB;
        for (int i = 0; i < 4; ++i) {
            k_split<<<dim3((n4 + 255) / 256), dim3(256), 0, stream>>>(x, xh, xl, n4);
            k_gemm_bb<<<ggrid(N_NODES, NHID), dim3(256), 0, stream>>>(
                xh, xl, wTh + (size_t)(phase * 4 + i) * NHID * NHID,
                wTl + (size_t)(phase * 4 + i) * NHID * NHID,
                nullptr, ybuf, N_NODES, NHID, NHID, NHID);
            k_spmm<<<dim3((N_NODES / 4) * 8), dim3(256), 0, stream>>>(
                ybuf, x, rowptr, csrc, cw, B + (size_t)i * NHID, (i == 0) ? 1 : 0, xn);
            float* tmp = x; x = xn; xn = tmp;
        }
    }

    // ---- final split (for out GEMMs + zloss) ----
    k_split<<<dim3((n4 + 255) / 256), dim3(256), 0, stream>>>(x, xh, xl, n4);

    // ---- output projections ----
    {
        short *ph = oWh, *pl = oWl;
        float* oo = out;
        size_t rowoff = 0;
        for (int i = 0; i < 3; ++i) {
            k_gemm_bb<<<ggrid(SD[i], FD[i]), dim3(256), 0, stream>>>(
                xh + rowoff * NHID, xl + rowoff * NHID, ph, pl, outB[i], oo,
                SD[i], FD[i], NHID, NHID);
            ph += (size_t)FD[i] * NHID; pl += (size_t)FD[i] * NHID;
            oo += (size_t)SD[i] * FD[i];
            rowoff += SD[i];
        }
    }

    // ---- losses ----
    k_zloss<<<dim3(NBLK * (NBLK + 1) / 2), dim3(256), 0, stream>>>(xh, xl, adj, accum);
    k_recon<<<dim3(S0), dim3(256), 0, stream>>>(out, X0, accum);
    k_final<<<dim3(1), dim3(64), 0, stream>>>(accum, out);
}